// Round 4
// baseline (745.723 us; speedup 1.0000x reference)
//
#include <hip/hip_runtime.h>
#include <math.h>

// Problem constants (from reference)
constexpr int NN  = 100000;   // nodes
constexpr int EE  = 1600000;  // edges
constexpr int IND = 128;      // input dim
constexpr int HID = 64;       // hidden dim
constexpr int NB_SCAN = (NN + 255) / 256;   // 391 scan blocks

// ---------------- zero / histogram / scan / permute (CSR build by col) ------

__global__ __launch_bounds__(256) void k_zero(int* __restrict__ p, int n) {
    int i = blockIdx.x * 256 + threadIdx.x;
    if (i < n) p[i] = 0;
}

__global__ __launch_bounds__(256) void k_hist(const int* __restrict__ col, int* __restrict__ cnt) {
    int e = blockIdx.x * 256 + threadIdx.x;
    if (e < EE) atomicAdd(&cnt[col[e]], 1);
}

__global__ __launch_bounds__(256) void k_scanA(const int* __restrict__ cnt, int* __restrict__ base,
                                               int* __restrict__ bsum) {
    __shared__ int tmp[256];
    int t = threadIdx.x, i = blockIdx.x * 256 + t;
    int v = (i < NN) ? cnt[i] : 0;
    tmp[t] = v;
    __syncthreads();
    #pragma unroll
    for (int off = 1; off < 256; off <<= 1) {
        int add = (t >= off) ? tmp[t - off] : 0;
        __syncthreads();
        tmp[t] += add;
        __syncthreads();
    }
    if (i < NN) base[i] = tmp[t] - v;
    if (t == 255) bsum[blockIdx.x] = tmp[255];
}

__global__ __launch_bounds__(512) void k_scanB(int* __restrict__ bsum) {
    __shared__ int tmp[512];
    int t = threadIdx.x;
    int v = (t < NB_SCAN) ? bsum[t] : 0;
    tmp[t] = v;
    __syncthreads();
    #pragma unroll
    for (int off = 1; off < 512; off <<= 1) {
        int add = (t >= off) ? tmp[t - off] : 0;
        __syncthreads();
        tmp[t] += add;
        __syncthreads();
    }
    if (t < NB_SCAN) bsum[t] = tmp[t] - v;
}

__global__ __launch_bounds__(256) void k_finalize(int* __restrict__ base, const int* __restrict__ bsum,
                                                  const int* __restrict__ cnt, int* __restrict__ cursor,
                                                  float* __restrict__ dinv) {
    int i = blockIdx.x * 256 + threadIdx.x;
    if (i < NN) {
        int v = base[i] + bsum[blockIdx.x];
        base[i] = v;
        cursor[i] = v;
        dinv[i] = rsqrtf((float)(cnt[i] + 1));   // +1 = self-loop
    }
}

__global__ __launch_bounds__(256) void k_permute(const int* __restrict__ row, const int* __restrict__ col,
                                                 int* __restrict__ cursor, int* __restrict__ prow) {
    int e = blockIdx.x * 256 + threadIdx.x;
    if (e < EE) {
        int c = col[e];
        int p = atomicAdd(&cursor[c], 1);
        prow[p] = row[e];
    }
}

// ---------------- fc: h = x @ fc_w + fc_b  (128 -> 64) ----------------------
// 128-row x 64-col tile, 256 threads, 8x4 per thread.
// A staged TRANSPOSED (sx[k][r], pitch 132): A-reads are 4-address float4
// broadcasts (conflict-free); B-reads 2-way (free).

__global__ __launch_bounds__(256) void k_fc(const float* __restrict__ x, const float* __restrict__ w,
                                            const float* __restrict__ b, float* __restrict__ h) {
    __shared__ float sw[IND * HID];     // 32 KB  [k][c]
    __shared__ float sx[32][132];       // 16.9 KB transposed chunk [k][r]
    const int tx = threadIdx.x;
    for (int i = tx; i < IND * HID; i += 256) sw[i] = w[i];

    const int tc = tx & 15, tr = tx >> 4;
    const int c0 = tc * 4, r0 = tr * 8;
    const int rbase = blockIdx.x * 128;

    float4 bb = *(const float4*)&b[c0];
    float acc[8][4];
    #pragma unroll
    for (int i = 0; i < 8; ++i) {
        acc[i][0] = bb.x; acc[i][1] = bb.y; acc[i][2] = bb.z; acc[i][3] = bb.w;
    }

    for (int kc = 0; kc < 4; ++kc) {
        __syncthreads();   // iter0: protect sw staging; later: protect sx reads
        #pragma unroll
        for (int p = 0; p < 4; ++p) {
            int r  = (tx >> 3) + p * 32;
            int k4 = (tx & 7) * 4;
            int rg = rbase + r;
            float4 v = (rg < NN) ? *(const float4*)&x[rg * IND + kc * 32 + k4]
                                 : make_float4(0.f, 0.f, 0.f, 0.f);
            sx[k4 + 0][r] = v.x; sx[k4 + 1][r] = v.y;
            sx[k4 + 2][r] = v.z; sx[k4 + 3][r] = v.w;
        }
        __syncthreads();
        #pragma unroll
        for (int k = 0; k < 32; ++k) {
            float4 a0 = *(const float4*)&sx[k][r0];
            float4 a1 = *(const float4*)&sx[k][r0 + 4];
            float4 bv = *(const float4*)&sw[(kc * 32 + k) * HID + c0];
            acc[0][0] += a0.x * bv.x; acc[0][1] += a0.x * bv.y; acc[0][2] += a0.x * bv.z; acc[0][3] += a0.x * bv.w;
            acc[1][0] += a0.y * bv.x; acc[1][1] += a0.y * bv.y; acc[1][2] += a0.y * bv.z; acc[1][3] += a0.y * bv.w;
            acc[2][0] += a0.z * bv.x; acc[2][1] += a0.z * bv.y; acc[2][2] += a0.z * bv.z; acc[2][3] += a0.z * bv.w;
            acc[3][0] += a0.w * bv.x; acc[3][1] += a0.w * bv.y; acc[3][2] += a0.w * bv.z; acc[3][3] += a0.w * bv.w;
            acc[4][0] += a1.x * bv.x; acc[4][1] += a1.x * bv.y; acc[4][2] += a1.x * bv.z; acc[4][3] += a1.x * bv.w;
            acc[5][0] += a1.y * bv.x; acc[5][1] += a1.y * bv.y; acc[5][2] += a1.y * bv.z; acc[5][3] += a1.y * bv.w;
            acc[6][0] += a1.z * bv.x; acc[6][1] += a1.z * bv.y; acc[6][2] += a1.z * bv.z; acc[6][3] += a1.z * bv.w;
            acc[7][0] += a1.w * bv.x; acc[7][1] += a1.w * bv.y; acc[7][2] += a1.w * bv.z; acc[7][3] += a1.w * bv.w;
        }
    }

    #pragma unroll
    for (int i = 0; i < 8; ++i) {
        int rg = rbase + r0 + i;
        if (rg < NN)
            *(float4*)&h[rg * HID + c0] = make_float4(acc[i][0], acc[i][1], acc[i][2], acc[i][3]);
    }
}

// ---------------- conv transform: md = (hin @ W) * dinv  (64 -> 64) ---------

__global__ __launch_bounds__(256) void k_mm(const float* __restrict__ hin, const float* __restrict__ w,
                                            const float* __restrict__ dinv, float* __restrict__ md) {
    __shared__ float sw[HID * HID];     // 16 KB
    __shared__ float sh[64][132];       // 33.8 KB transposed [k][r]
    const int tx = threadIdx.x;
    for (int i = tx; i < HID * HID; i += 256) sw[i] = w[i];

    const int tc = tx & 15, tr = tx >> 4;
    const int c0 = tc * 4, r0 = tr * 8;
    const int rbase = blockIdx.x * 128;

    #pragma unroll
    for (int p = 0; p < 8; ++p) {
        int r  = (tx >> 4) + p * 16;
        int k4 = (tx & 15) * 4;
        int rg = rbase + r;
        float4 v = (rg < NN) ? *(const float4*)&hin[rg * HID + k4]
                             : make_float4(0.f, 0.f, 0.f, 0.f);
        sh[k4 + 0][r] = v.x; sh[k4 + 1][r] = v.y;
        sh[k4 + 2][r] = v.z; sh[k4 + 3][r] = v.w;
    }
    __syncthreads();

    float acc[8][4] = {};
    #pragma unroll
    for (int k = 0; k < 64; ++k) {
        float4 a0 = *(const float4*)&sh[k][r0];
        float4 a1 = *(const float4*)&sh[k][r0 + 4];
        float4 bv = *(const float4*)&sw[k * HID + c0];
        acc[0][0] += a0.x * bv.x; acc[0][1] += a0.x * bv.y; acc[0][2] += a0.x * bv.z; acc[0][3] += a0.x * bv.w;
        acc[1][0] += a0.y * bv.x; acc[1][1] += a0.y * bv.y; acc[1][2] += a0.y * bv.z; acc[1][3] += a0.y * bv.w;
        acc[2][0] += a0.z * bv.x; acc[2][1] += a0.z * bv.y; acc[2][2] += a0.z * bv.z; acc[2][3] += a0.z * bv.w;
        acc[3][0] += a0.w * bv.x; acc[3][1] += a0.w * bv.y; acc[3][2] += a0.w * bv.z; acc[3][3] += a0.w * bv.w;
        acc[4][0] += a1.x * bv.x; acc[4][1] += a1.x * bv.y; acc[4][2] += a1.x * bv.z; acc[4][3] += a1.x * bv.w;
        acc[5][0] += a1.y * bv.x; acc[5][1] += a1.y * bv.y; acc[5][2] += a1.y * bv.z; acc[5][3] += a1.y * bv.w;
        acc[6][0] += a1.z * bv.x; acc[6][1] += a1.z * bv.y; acc[6][2] += a1.z * bv.z; acc[6][3] += a1.z * bv.w;
        acc[7][0] += a1.w * bv.x; acc[7][1] += a1.w * bv.y; acc[7][2] += a1.w * bv.z; acc[7][3] += a1.w * bv.w;
    }

    #pragma unroll
    for (int i = 0; i < 8; ++i) {
        int rg = rbase + r0 + i;
        if (rg < NN) {
            float di = dinv[rg];
            *(float4*)&md[rg * HID + c0] =
                make_float4(acc[i][0] * di, acc[i][1] * di, acc[i][2] * di, acc[i][3] * di);
        }
    }
}

// ---------------- gather conv1: h1 = relu(dinv*(self + sum md[r]) + b) ------

__global__ __launch_bounds__(256) void k_gather(const float* __restrict__ md, const int* __restrict__ prow,
                                                const int* __restrict__ base, const int* __restrict__ cnt,
                                                const float* __restrict__ dinv, const float* __restrict__ b,
                                                float* __restrict__ hout) {
    int lane = threadIdx.x & 63;
    int wid  = (blockIdx.x * blockDim.x + threadIdx.x) >> 6;
    int nwv  = (gridDim.x * blockDim.x) >> 6;
    float bj = b[lane];
    for (int i = wid; i < NN; i += nwv) {
        int s = base[i], n = cnt[i];
        float acc = md[i * HID + lane];
        int e = 0;
        for (; e + 4 <= n; e += 4) {
            int r0 = prow[s + e],     r1 = prow[s + e + 1];
            int r2 = prow[s + e + 2], r3 = prow[s + e + 3];
            float v0 = md[r0 * HID + lane], v1 = md[r1 * HID + lane];
            float v2 = md[r2 * HID + lane], v3 = md[r3 * HID + lane];
            acc += (v0 + v1) + (v2 + v3);
        }
        for (; e < n; ++e) acc += md[prow[s + e] * HID + lane];
        float v = dinv[i] * acc + bj;
        hout[i * HID + lane] = v > 0.f ? v : 0.f;
    }
}

// ---------------- gather conv2 fused with scores ----------------------------

__global__ __launch_bounds__(256) void k_gather2s(const float* __restrict__ md, const int* __restrict__ prow,
        const int* __restrict__ base, const int* __restrict__ cnt, const float* __restrict__ dinv,
        const float* __restrict__ b, const float* __restrict__ nw, const float* __restrict__ nb,
        const float* __restrict__ ew, float* __restrict__ out_node,
        float* __restrict__ ssrc, float* __restrict__ sdst) {
    int lane = threadIdx.x & 63;
    int wid  = (blockIdx.x * blockDim.x + threadIdx.x) >> 6;
    int nwv  = (gridDim.x * blockDim.x) >> 6;
    float bj = b[lane];
    float w0 = nw[lane], w1 = ew[lane], w2 = ew[64 + lane];
    float nb0 = nb[0];
    for (int i = wid; i < NN; i += nwv) {
        int s = base[i], n = cnt[i];
        float acc = md[i * HID + lane];
        int e = 0;
        for (; e + 4 <= n; e += 4) {
            int r0 = prow[s + e],     r1 = prow[s + e + 1];
            int r2 = prow[s + e + 2], r3 = prow[s + e + 3];
            float v0 = md[r0 * HID + lane], v1 = md[r1 * HID + lane];
            float v2 = md[r2 * HID + lane], v3 = md[r3 * HID + lane];
            acc += (v0 + v1) + (v2 + v3);
        }
        for (; e < n; ++e) acc += md[prow[s + e] * HID + lane];
        float v = dinv[i] * acc + bj;
        v = v > 0.f ? v : 0.f;
        float a = v * w0, s1 = v * w1, s2 = v * w2;
        #pragma unroll
        for (int off = 32; off; off >>= 1) {
            a  += __shfl_xor(a,  off, 64);
            s1 += __shfl_xor(s1, off, 64);
            s2 += __shfl_xor(s2, off, 64);
        }
        if (lane == 0) {
            out_node[i] = 1.f / (1.f + expf(-(a + nb0)));
            ssrc[i] = s1;
            sdst[i] = s2;
        }
    }
}

// ---------------- edge scores ----------------

__global__ __launch_bounds__(256) void k_edge(const int* __restrict__ row, const int* __restrict__ col,
                                              const float* __restrict__ ssrc, const float* __restrict__ sdst,
                                              const float* __restrict__ eb, float* __restrict__ out_edge) {
    int stride = gridDim.x * 256;
    float eb0 = eb[0];
    for (int i = blockIdx.x * 256 + threadIdx.x; i < EE; i += stride) {
        float z = ssrc[row[i]] + sdst[col[i]] + eb0;
        out_edge[i] = 1.f / (1.f + expf(-z));
    }
}

extern "C" void kernel_launch(void* const* d_in, const int* in_sizes, int n_in,
                              void* d_out, int out_size, void* d_ws, size_t ws_size,
                              hipStream_t stream) {
    const float* x    = (const float*)d_in[0];
    const int*   ei   = (const int*)d_in[1];
    const float* fc_w = (const float*)d_in[2];
    const float* fc_b = (const float*)d_in[3];
    const float* c1w  = (const float*)d_in[4];
    const float* c1b  = (const float*)d_in[5];
    const float* c2w  = (const float*)d_in[6];
    const float* c2b  = (const float*)d_in[7];
    const float* nw   = (const float*)d_in[8];
    const float* nb   = (const float*)d_in[9];
    const float* ew   = (const float*)d_in[10];
    const float* eb   = (const float*)d_in[11];
    const int* row = ei;        // edge_index[0]
    const int* col = ei + EE;   // edge_index[1]

    // workspace layout
    constexpr int NP = 102400;
    float* ws     = (float*)d_ws;
    float* dinv   = ws;
    float* ssrc   = ws + NP;
    float* sdst   = ws + 2 * NP;
    int*   cnt    = (int*)(ws + 3 * NP);
    int*   base   = (int*)(ws + 4 * NP);
    int*   cursor = (int*)(ws + 5 * NP);
    int*   bsum   = (int*)(ws + 6 * NP);          // 512 ints
    int*   prow   = (int*)(ws + 6 * NP + 512);    // EE ints
    float* A      = ws + 6 * NP + 512 + EE;       // h  [N*HID]
    float* B      = A + (size_t)NN * HID;         // md [N*HID]

    float* out_edge = (float*)d_out;
    float* out_node = out_edge + EE;

    const int nbN = (NN + 255) / 256;   // 391
    const int nbE = (EE + 255) / 256;   // 6250
    const int nbG = (NN + 127) / 128;   // 782 GEMM tiles (128 rows each)

    // ---- CSR build (by col) + degree norm ----
    k_zero    <<<nbN, 256, 0, stream>>>(cnt, NN);
    k_hist    <<<nbE, 256, 0, stream>>>(col, cnt);
    k_scanA   <<<NB_SCAN, 256, 0, stream>>>(cnt, base, bsum);
    k_scanB   <<<1, 512, 0, stream>>>(bsum);
    k_finalize<<<NB_SCAN, 256, 0, stream>>>(base, bsum, cnt, cursor, dinv);
    k_permute <<<nbE, 256, 0, stream>>>(row, col, cursor, prow);

    // ---- fc, conv1 transform, conv1 gather ----
    k_fc    <<<nbG, 256, 0, stream>>>(x, fc_w, fc_b, A);
    k_mm    <<<nbG, 256, 0, stream>>>(A, c1w, dinv, B);
    k_gather<<<2048, 256, 0, stream>>>(B, prow, base, cnt, dinv, c1b, A);

    // ---- conv2 transform + gather fused with scores ----
    k_mm      <<<nbG, 256, 0, stream>>>(A, c2w, dinv, B);
    k_gather2s<<<2048, 256, 0, stream>>>(B, prow, base, cnt, dinv, c2b,
                                         nw, nb, ew, out_node, ssrc, sdst);

    // ---- edge scores ----
    k_edge<<<2048, 256, 0, stream>>>(row, col, ssrc, sdst, eb, out_edge);
}

// Round 5
// 438.046 us; speedup vs baseline: 1.7024x; 1.7024x over previous
//
#include <hip/hip_runtime.h>
#include <math.h>

// Problem constants (from reference)
constexpr int NN  = 100000;   // nodes
constexpr int EE  = 1600000;  // edges
constexpr int IND = 128;      // input dim
constexpr int HID = 64;       // hidden dim
constexpr int NB_SCAN = (NN + 255) / 256;   // 391 scan blocks

// ---------------- zero / histogram / scan / permute (CSR build by col) ------

__global__ __launch_bounds__(256) void k_zero(int* __restrict__ p, int n) {
    int i = blockIdx.x * 256 + threadIdx.x;
    if (i < n) p[i] = 0;
}

__global__ __launch_bounds__(256) void k_hist(const int* __restrict__ col, int* __restrict__ cnt) {
    int e = blockIdx.x * 256 + threadIdx.x;
    if (e < EE) atomicAdd(&cnt[col[e]], 1);
}

__global__ __launch_bounds__(256) void k_scanA(const int* __restrict__ cnt, int* __restrict__ base,
                                               int* __restrict__ bsum) {
    __shared__ int tmp[256];
    int t = threadIdx.x, i = blockIdx.x * 256 + t;
    int v = (i < NN) ? cnt[i] : 0;
    tmp[t] = v;
    __syncthreads();
    #pragma unroll
    for (int off = 1; off < 256; off <<= 1) {
        int add = (t >= off) ? tmp[t - off] : 0;
        __syncthreads();
        tmp[t] += add;
        __syncthreads();
    }
    if (i < NN) base[i] = tmp[t] - v;
    if (t == 255) bsum[blockIdx.x] = tmp[255];
}

__global__ __launch_bounds__(512) void k_scanB(int* __restrict__ bsum) {
    __shared__ int tmp[512];
    int t = threadIdx.x;
    int v = (t < NB_SCAN) ? bsum[t] : 0;
    tmp[t] = v;
    __syncthreads();
    #pragma unroll
    for (int off = 1; off < 512; off <<= 1) {
        int add = (t >= off) ? tmp[t - off] : 0;
        __syncthreads();
        tmp[t] += add;
        __syncthreads();
    }
    if (t < NB_SCAN) bsum[t] = tmp[t] - v;
}

__global__ __launch_bounds__(256) void k_finalize(int* __restrict__ base, const int* __restrict__ bsum,
                                                  const int* __restrict__ cnt, int* __restrict__ cursor,
                                                  float* __restrict__ dinv) {
    int i = blockIdx.x * 256 + threadIdx.x;
    if (i < NN) {
        int v = base[i] + bsum[blockIdx.x];
        base[i] = v;
        cursor[i] = v;
        dinv[i] = rsqrtf((float)(cnt[i] + 1));   // +1 = self-loop
    }
}

__global__ __launch_bounds__(256) void k_permute(const int* __restrict__ row, const int* __restrict__ col,
                                                 int* __restrict__ cursor, int* __restrict__ prow) {
    int e = blockIdx.x * 256 + threadIdx.x;
    if (e < EE) {
        int c = col[e];
        int p = atomicAdd(&cursor[c], 1);
        prow[p] = row[e];
    }
}

// ---------------- fc: h = x @ fc_w + fc_b  (128 -> 64) ----------------------
// 128 rows x 64 cols per block, 256 threads, 8x4 per thread.
// A streamed from global into registers (duplicate lane addresses merge in
// the coalescer -> 1x traffic, zero DS ops). B (weights) in LDS, float4
// reads = 2-way bank aliasing (free). #pragma unroll 1 bounds VGPR (~100,
// no spill - the round-4 lesson).

__global__ __launch_bounds__(256) void k_fc(const float* __restrict__ x, const float* __restrict__ w,
                                            const float* __restrict__ b, float* __restrict__ h) {
    __shared__ float sw[IND * HID];     // 32 KB  [k][c]
    const int tx = threadIdx.x;
    for (int i = tx; i < IND * HID; i += 256) sw[i] = w[i];

    const int tc = tx & 15;
    const int gr = tx >> 4;             // 0..15: row-group within block
    const int c0 = tc * 4;
    const int rbase = blockIdx.x * 128 + gr * 8;

    int o[8];                           // clamped row offsets (32-bit: N*IND < 2^31)
    #pragma unroll
    for (int i = 0; i < 8; ++i) {
        int rg = rbase + i;
        o[i] = (rg < NN ? rg : 0) * IND;
    }
    __syncthreads();

    float4 bb = *(const float4*)&b[c0];
    float acc[8][4];
    #pragma unroll
    for (int i = 0; i < 8; ++i) {
        acc[i][0] = bb.x; acc[i][1] = bb.y; acc[i][2] = bb.z; acc[i][3] = bb.w;
    }

    #pragma unroll 1
    for (int kk = 0; kk < IND; kk += 4) {
        float4 a[8];
        #pragma unroll
        for (int i = 0; i < 8; ++i) a[i] = *(const float4*)(x + o[i] + kk);
        float4 b0 = *(const float4*)&sw[(kk + 0) * HID + c0];
        float4 b1 = *(const float4*)&sw[(kk + 1) * HID + c0];
        float4 b2 = *(const float4*)&sw[(kk + 2) * HID + c0];
        float4 b3 = *(const float4*)&sw[(kk + 3) * HID + c0];
        #pragma unroll
        for (int i = 0; i < 8; ++i) {
            acc[i][0] += a[i].x * b0.x + a[i].y * b1.x + a[i].z * b2.x + a[i].w * b3.x;
            acc[i][1] += a[i].x * b0.y + a[i].y * b1.y + a[i].z * b2.y + a[i].w * b3.y;
            acc[i][2] += a[i].x * b0.z + a[i].y * b1.z + a[i].z * b2.z + a[i].w * b3.z;
            acc[i][3] += a[i].x * b0.w + a[i].y * b1.w + a[i].z * b2.w + a[i].w * b3.w;
        }
    }

    #pragma unroll
    for (int i = 0; i < 8; ++i) {
        int rg = rbase + i;
        if (rg < NN)
            *(float4*)&h[rg * HID + c0] = make_float4(acc[i][0], acc[i][1], acc[i][2], acc[i][3]);
    }
}

// ---------------- conv transform: md = (hin @ W) * dinv  (64 -> 64) ---------

__global__ __launch_bounds__(256) void k_mm(const float* __restrict__ hin, const float* __restrict__ w,
                                            const float* __restrict__ dinv, float* __restrict__ md) {
    __shared__ float sw[HID * HID];     // 16 KB
    const int tx = threadIdx.x;
    for (int i = tx; i < HID * HID; i += 256) sw[i] = w[i];

    const int tc = tx & 15;
    const int gr = tx >> 4;
    const int c0 = tc * 4;
    const int rbase = blockIdx.x * 128 + gr * 8;

    int o[8];
    #pragma unroll
    for (int i = 0; i < 8; ++i) {
        int rg = rbase + i;
        o[i] = (rg < NN ? rg : 0) * HID;
    }
    __syncthreads();

    float acc[8][4] = {};

    #pragma unroll 1
    for (int kk = 0; kk < HID; kk += 4) {
        float4 a[8];
        #pragma unroll
        for (int i = 0; i < 8; ++i) a[i] = *(const float4*)(hin + o[i] + kk);
        float4 b0 = *(const float4*)&sw[(kk + 0) * HID + c0];
        float4 b1 = *(const float4*)&sw[(kk + 1) * HID + c0];
        float4 b2 = *(const float4*)&sw[(kk + 2) * HID + c0];
        float4 b3 = *(const float4*)&sw[(kk + 3) * HID + c0];
        #pragma unroll
        for (int i = 0; i < 8; ++i) {
            acc[i][0] += a[i].x * b0.x + a[i].y * b1.x + a[i].z * b2.x + a[i].w * b3.x;
            acc[i][1] += a[i].x * b0.y + a[i].y * b1.y + a[i].z * b2.y + a[i].w * b3.y;
            acc[i][2] += a[i].x * b0.z + a[i].y * b1.z + a[i].z * b2.z + a[i].w * b3.z;
            acc[i][3] += a[i].x * b0.w + a[i].y * b1.w + a[i].z * b2.w + a[i].w * b3.w;
        }
    }

    #pragma unroll
    for (int i = 0; i < 8; ++i) {
        int rg = rbase + i;
        if (rg < NN) {
            float di = dinv[rg];
            *(float4*)&md[rg * HID + c0] =
                make_float4(acc[i][0] * di, acc[i][1] * di, acc[i][2] * di, acc[i][3] * di);
        }
    }
}

// ---------------- gather conv1: h1 = relu(dinv*(self + sum md[r]) + b) ------

__global__ __launch_bounds__(256) void k_gather(const float* __restrict__ md, const int* __restrict__ prow,
                                                const int* __restrict__ base, const int* __restrict__ cnt,
                                                const float* __restrict__ dinv, const float* __restrict__ b,
                                                float* __restrict__ hout) {
    int lane = threadIdx.x & 63;
    int wid  = (blockIdx.x * blockDim.x + threadIdx.x) >> 6;
    int nwv  = (gridDim.x * blockDim.x) >> 6;
    float bj = b[lane];
    for (int i = wid; i < NN; i += nwv) {
        int s = base[i], n = cnt[i];
        float acc = md[i * HID + lane];
        int e = 0;
        for (; e + 4 <= n; e += 4) {
            int r0 = prow[s + e],     r1 = prow[s + e + 1];
            int r2 = prow[s + e + 2], r3 = prow[s + e + 3];
            float v0 = md[r0 * HID + lane], v1 = md[r1 * HID + lane];
            float v2 = md[r2 * HID + lane], v3 = md[r3 * HID + lane];
            acc += (v0 + v1) + (v2 + v3);
        }
        for (; e < n; ++e) acc += md[prow[s + e] * HID + lane];
        float v = dinv[i] * acc + bj;
        hout[i * HID + lane] = v > 0.f ? v : 0.f;
    }
}

// ---------------- gather conv2 fused with scores ----------------------------

__global__ __launch_bounds__(256) void k_gather2s(const float* __restrict__ md, const int* __restrict__ prow,
        const int* __restrict__ base, const int* __restrict__ cnt, const float* __restrict__ dinv,
        const float* __restrict__ b, const float* __restrict__ nw, const float* __restrict__ nb,
        const float* __restrict__ ew, float* __restrict__ out_node,
        float* __restrict__ ssrc, float* __restrict__ sdst) {
    int lane = threadIdx.x & 63;
    int wid  = (blockIdx.x * blockDim.x + threadIdx.x) >> 6;
    int nwv  = (gridDim.x * blockDim.x) >> 6;
    float bj = b[lane];
    float w0 = nw[lane], w1 = ew[lane], w2 = ew[64 + lane];
    float nb0 = nb[0];
    for (int i = wid; i < NN; i += nwv) {
        int s = base[i], n = cnt[i];
        float acc = md[i * HID + lane];
        int e = 0;
        for (; e + 4 <= n; e += 4) {
            int r0 = prow[s + e],     r1 = prow[s + e + 1];
            int r2 = prow[s + e + 2], r3 = prow[s + e + 3];
            float v0 = md[r0 * HID + lane], v1 = md[r1 * HID + lane];
            float v2 = md[r2 * HID + lane], v3 = md[r3 * HID + lane];
            acc += (v0 + v1) + (v2 + v3);
        }
        for (; e < n; ++e) acc += md[prow[s + e] * HID + lane];
        float v = dinv[i] * acc + bj;
        v = v > 0.f ? v : 0.f;
        float a = v * w0, s1 = v * w1, s2 = v * w2;
        #pragma unroll
        for (int off = 32; off; off >>= 1) {
            a  += __shfl_xor(a,  off, 64);
            s1 += __shfl_xor(s1, off, 64);
            s2 += __shfl_xor(s2, off, 64);
        }
        if (lane == 0) {
            out_node[i] = 1.f / (1.f + expf(-(a + nb0)));
            ssrc[i] = s1;
            sdst[i] = s2;
        }
    }
}

// ---------------- edge scores ----------------

__global__ __launch_bounds__(256) void k_edge(const int* __restrict__ row, const int* __restrict__ col,
                                              const float* __restrict__ ssrc, const float* __restrict__ sdst,
                                              const float* __restrict__ eb, float* __restrict__ out_edge) {
    int stride = gridDim.x * 256;
    float eb0 = eb[0];
    for (int i = blockIdx.x * 256 + threadIdx.x; i < EE; i += stride) {
        float z = ssrc[row[i]] + sdst[col[i]] + eb0;
        out_edge[i] = 1.f / (1.f + expf(-z));
    }
}

extern "C" void kernel_launch(void* const* d_in, const int* in_sizes, int n_in,
                              void* d_out, int out_size, void* d_ws, size_t ws_size,
                              hipStream_t stream) {
    const float* x    = (const float*)d_in[0];
    const int*   ei   = (const int*)d_in[1];
    const float* fc_w = (const float*)d_in[2];
    const float* fc_b = (const float*)d_in[3];
    const float* c1w  = (const float*)d_in[4];
    const float* c1b  = (const float*)d_in[5];
    const float* c2w  = (const float*)d_in[6];
    const float* c2b  = (const float*)d_in[7];
    const float* nw   = (const float*)d_in[8];
    const float* nb   = (const float*)d_in[9];
    const float* ew   = (const float*)d_in[10];
    const float* eb   = (const float*)d_in[11];
    const int* row = ei;        // edge_index[0]
    const int* col = ei + EE;   // edge_index[1]

    // workspace layout
    constexpr int NP = 102400;
    float* ws     = (float*)d_ws;
    float* dinv   = ws;
    float* ssrc   = ws + NP;
    float* sdst   = ws + 2 * NP;
    int*   cnt    = (int*)(ws + 3 * NP);
    int*   base   = (int*)(ws + 4 * NP);
    int*   cursor = (int*)(ws + 5 * NP);
    int*   bsum   = (int*)(ws + 6 * NP);          // 512 ints
    int*   prow   = (int*)(ws + 6 * NP + 512);    // EE ints
    float* A      = ws + 6 * NP + 512 + EE;       // h  [N*HID]
    float* B      = A + (size_t)NN * HID;         // md [N*HID]

    float* out_edge = (float*)d_out;
    float* out_node = out_edge + EE;

    const int nbN = (NN + 255) / 256;   // 391
    const int nbE = (EE + 255) / 256;   // 6250
    const int nbG = (NN + 127) / 128;   // 782 GEMM tiles (128 rows each)

    // ---- CSR build (by col) + degree norm ----
    k_zero    <<<nbN, 256, 0, stream>>>(cnt, NN);
    k_hist    <<<nbE, 256, 0, stream>>>(col, cnt);
    k_scanA   <<<NB_SCAN, 256, 0, stream>>>(cnt, base, bsum);
    k_scanB   <<<1, 512, 0, stream>>>(bsum);
    k_finalize<<<NB_SCAN, 256, 0, stream>>>(base, bsum, cnt, cursor, dinv);
    k_permute <<<nbE, 256, 0, stream>>>(row, col, cursor, prow);

    // ---- fc, conv1 transform, conv1 gather ----
    k_fc    <<<nbG, 256, 0, stream>>>(x, fc_w, fc_b, A);
    k_mm    <<<nbG, 256, 0, stream>>>(A, c1w, dinv, B);
    k_gather<<<2048, 256, 0, stream>>>(B, prow, base, cnt, dinv, c1b, A);

    // ---- conv2 transform + gather fused with scores ----
    k_mm      <<<nbG, 256, 0, stream>>>(A, c2w, dinv, B);
    k_gather2s<<<2048, 256, 0, stream>>>(B, prow, base, cnt, dinv, c2b,
                                         nw, nb, ew, out_node, ssrc, sdst);

    // ---- edge scores ----
    k_edge<<<2048, 256, 0, stream>>>(row, col, ssrc, sdst, eb, out_edge);
}